// Round 1
// baseline (414.772 us; speedup 1.0000x reference)
//
#include <hip/hip_runtime.h>

#define NSND  49152
#define NRECV 115200
#define BM    128
#define BLKS_PER_BATCH 900   // 115200 / 128
#define NBLK  1800           // 2 * 900

typedef __bf16 bx8 __attribute__((ext_vector_type(8)));
typedef float  fx4 __attribute__((ext_vector_type(4)));

__device__ __forceinline__ unsigned short f2bf(float f) {
  unsigned u = __float_as_uint(f);
  u += 0x7FFFu + ((u >> 16) & 1u);   // round-to-nearest-even
  return (unsigned short)(u >> 16);
}

// ---------- prep 1: c1[n] = b1f[n] + sum_i ef_sum[i] * w1f[256+i][n] ----------
__global__ void prep_c1(const float* __restrict__ w1e, const float* __restrict__ b1e,
                        const float* __restrict__ w2e, const float* __restrict__ b2e,
                        const float* __restrict__ w1f, const float* __restrict__ b1f,
                        float* __restrict__ c1) {
  __shared__ float s_sum[64];
  __shared__ float s_ef[64];
  int t = threadIdx.x;
  if (t < 64) {
    float w = w1e[t], b = b1e[t];
    float acc = 0.f;
    for (int k = 0; k < 4; ++k) {
      float v = (float)k * w + b;
      acc += v / (1.f + expf(-v));      // silu, summed over the 4 edge-attr values
    }
    s_sum[t] = acc;
  }
  __syncthreads();
  if (t < 64) {
    float acc = 4.f * b2e[t];
    for (int j = 0; j < 64; ++j) acc += s_sum[j] * w2e[j * 64 + t];
    s_ef[t] = acc;
  }
  __syncthreads();
  if (t < 256) {
    float acc = b1f[t];
    for (int i = 0; i < 64; ++i) acc += s_ef[i] * w1f[(256 + i) * 256 + t];
    c1[t] = acc;
  }
}

// ---------- prep 2: weights -> bf16, MFMA-B-fragment-contiguous layout ----------
// Layout: frag[ct (16 col-tiles)][ks (8 k-steps)][lane (64)][8 bf16]
//   element = W[k][n], n = ct*16 + (lane&15), k = ks*32 + (lane>>4)*8 + j
__global__ void prep_w(const float* __restrict__ w1f, const float* __restrict__ w2f,
                       unsigned short* __restrict__ W1f, unsigned short* __restrict__ W2f) {
  int idx  = blockIdx.x * blockDim.x + threadIdx.x;   // 0..8191
  int lane = idx & 63;
  int ks   = (idx >> 6) & 7;
  int ct   = idx >> 9;
  int n     = ct * 16 + (lane & 15);
  int kbase = ks * 32 + (lane >> 4) * 8;
  unsigned p1[4], p2[4];
#pragma unroll
  for (int h = 0; h < 4; ++h) {
    int k = kbase + 2 * h;
    p1[h] = (unsigned)f2bf(w1f[k * 256 + n]) | ((unsigned)f2bf(w1f[(k + 1) * 256 + n]) << 16);
    p2[h] = (unsigned)f2bf(w2f[k * 256 + n]) | ((unsigned)f2bf(w2f[(k + 1) * 256 + n]) << 16);
  }
  uint4 v1 = make_uint4(p1[0], p1[1], p1[2], p1[3]);
  uint4 v2 = make_uint4(p2[0], p2[1], p2[2], p2[3]);
  *(uint4*)(W1f + (size_t)idx * 8) = v1;
  *(uint4*)(W2f + (size_t)idx * 8) = v2;
}

// ---------- main fused kernel ----------
// grid 1800, block 512 (8 waves: wr = wave>>1 in [0,4), wc = wave&1 in [0,2))
// per block: 128 receivers. LDS: one 128x256 bf16 tile (A, then reused for H),
// XOR-swizzled: byte(row,col) = (row*512 + col*2) ^ ((row&7)<<4)
__global__ __launch_bounds__(512) void heal_main(
    const float* __restrict__ x, const int* __restrict__ edge_src,
    const float* __restrict__ c1, const unsigned short* __restrict__ W1f,
    const unsigned short* __restrict__ W2f, const float* __restrict__ b2f,
    float* __restrict__ out) {
  __shared__ char lds[BM * 256 * 2];   // 64 KiB

  const int tid  = threadIdx.x;
  const int lane = tid & 63;
  const int wv   = tid >> 6;
  const int wr   = wv >> 1;
  const int wc   = wv & 1;

  const int blk = blockIdx.x;
  const int b   = blk / BLKS_PER_BATCH;
  const int r0  = (blk % BLKS_PER_BATCH) * BM;
  const float* xb = x + (size_t)b * NSND * 256;

  // ---- phase 1: gather-sum 4 source rows per receiver -> bf16 A tile in LDS ----
#pragma unroll 4
  for (int i = 0; i < 16; ++i) {
    int row = wv * 16 + i;                         // 0..127
    int r   = r0 + row;
    int4 s  = *(const int4*)(edge_src + 4 * (size_t)r);
    const float4* q0 = (const float4*)(xb + (size_t)s.x * 256) + lane;
    const float4* q1 = (const float4*)(xb + (size_t)s.y * 256) + lane;
    const float4* q2 = (const float4*)(xb + (size_t)s.z * 256) + lane;
    const float4* q3 = (const float4*)(xb + (size_t)s.w * 256) + lane;
    float4 a0 = *q0, a1 = *q1, a2 = *q2, a3 = *q3;
    float v0 = a0.x + a1.x + a2.x + a3.x;
    float v1 = a0.y + a1.y + a2.y + a3.y;
    float v2 = a0.z + a1.z + a2.z + a3.z;
    float v3 = a0.w + a1.w + a2.w + a3.w;
    unsigned lo = (unsigned)f2bf(v0) | ((unsigned)f2bf(v1) << 16);
    unsigned hi = (unsigned)f2bf(v2) | ((unsigned)f2bf(v3) << 16);
    unsigned byte = (unsigned)(row * 512 + lane * 8) ^ (unsigned)((row & 7) << 4);
    *(uint2*)(lds + byte) = make_uint2(lo, hi);
  }
  __syncthreads();

  fx4 acc[2][8];
#pragma unroll
  for (int mr = 0; mr < 2; ++mr)
#pragma unroll
    for (int nc = 0; nc < 8; ++nc) acc[mr][nc] = (fx4){0.f, 0.f, 0.f, 0.f};

  // ---- phase 2: GEMM1  (A[128x256] @ W1[256x256]) ----
  const bx8* W1v = (const bx8*)W1f;
  for (int ks = 0; ks < 8; ++ks) {
    bx8 afr[2];
#pragma unroll
    for (int mr = 0; mr < 2; ++mr) {
      int arow = wr * 32 + mr * 16 + (lane & 15);
      unsigned ab = (unsigned)(arow * 512 + ks * 64 + (lane >> 4) * 16) ^ (unsigned)((arow & 7) << 4);
      afr[mr] = *(const bx8*)(lds + ab);
    }
#pragma unroll
    for (int nc = 0; nc < 8; ++nc) {
      int ct = wc * 8 + nc;
      bx8 bfr = W1v[(ct * 8 + ks) * 64 + lane];
      acc[0][nc] = __builtin_amdgcn_mfma_f32_16x16x32_bf16(afr[0], bfr, acc[0][nc], 0, 0, 0);
      acc[1][nc] = __builtin_amdgcn_mfma_f32_16x16x32_bf16(afr[1], bfr, acc[1][nc], 0, 0, 0);
    }
  }
  __syncthreads();   // all A reads complete before overwriting the tile with H

  // ---- phase 3: h = silu(acc + c1) -> bf16 H tile (same LDS buffer) ----
  float c1v[8];
#pragma unroll
  for (int nc = 0; nc < 8; ++nc) c1v[nc] = c1[wc * 128 + nc * 16 + (lane & 15)];
#pragma unroll
  for (int mr = 0; mr < 2; ++mr)
#pragma unroll
    for (int nc = 0; nc < 8; ++nc) {
      int hcol = wc * 128 + nc * 16 + (lane & 15);
#pragma unroll
      for (int j = 0; j < 4; ++j) {
        float v = acc[mr][nc][j] + c1v[nc];
        float h = v / (1.f + __expf(-v));            // silu
        int hrow = wr * 32 + mr * 16 + (lane >> 4) * 4 + j;
        unsigned hb = (unsigned)(hrow * 512 + hcol * 2) ^ (unsigned)((hrow & 7) << 4);
        *(unsigned short*)(lds + hb) = f2bf(h);
      }
    }
  __syncthreads();

  // ---- phase 4: GEMM2  (H[128x256] @ W2[256x256]) ----
#pragma unroll
  for (int mr = 0; mr < 2; ++mr)
#pragma unroll
    for (int nc = 0; nc < 8; ++nc) acc[mr][nc] = (fx4){0.f, 0.f, 0.f, 0.f};
  const bx8* W2v = (const bx8*)W2f;
  for (int ks = 0; ks < 8; ++ks) {
    bx8 afr[2];
#pragma unroll
    for (int mr = 0; mr < 2; ++mr) {
      int arow = wr * 32 + mr * 16 + (lane & 15);
      unsigned ab = (unsigned)(arow * 512 + ks * 64 + (lane >> 4) * 16) ^ (unsigned)((arow & 7) << 4);
      afr[mr] = *(const bx8*)(lds + ab);
    }
#pragma unroll
    for (int nc = 0; nc < 8; ++nc) {
      int ct = wc * 8 + nc;
      bx8 bfr = W2v[(ct * 8 + ks) * 64 + lane];
      acc[0][nc] = __builtin_amdgcn_mfma_f32_16x16x32_bf16(afr[0], bfr, acc[0][nc], 0, 0, 0);
      acc[1][nc] = __builtin_amdgcn_mfma_f32_16x16x32_bf16(afr[1], bfr, acc[1][nc], 0, 0, 0);
    }
  }

  // ---- phase 5: out = acc + b2f ----
  size_t obase = ((size_t)b * NRECV + r0) * 256;
#pragma unroll
  for (int nc = 0; nc < 8; ++nc) {
    int col = wc * 128 + nc * 16 + (lane & 15);
    float bias = b2f[col];
#pragma unroll
    for (int mr = 0; mr < 2; ++mr)
#pragma unroll
      for (int j = 0; j < 4; ++j) {
        int row = wr * 32 + mr * 16 + (lane >> 4) * 4 + j;
        out[obase + (size_t)row * 256 + col] = acc[mr][nc][j] + bias;
      }
  }
}

extern "C" void kernel_launch(void* const* d_in, const int* in_sizes, int n_in,
                              void* d_out, int out_size, void* d_ws, size_t ws_size,
                              hipStream_t stream) {
  const float* x    = (const float*)d_in[0];
  const float* w1e  = (const float*)d_in[2];
  const float* b1e  = (const float*)d_in[3];
  const float* w2e  = (const float*)d_in[4];
  const float* b2e  = (const float*)d_in[5];
  const float* w1f  = (const float*)d_in[6];
  const float* b1f  = (const float*)d_in[7];
  const float* w2f  = (const float*)d_in[8];
  const float* b2f  = (const float*)d_in[9];
  const int* edge_src = (const int*)d_in[10];
  float* out = (float*)d_out;

  char* ws = (char*)d_ws;
  float* c1            = (float*)ws;                          // 1 KiB
  unsigned short* W1f  = (unsigned short*)(ws + 1024);        // 128 KiB
  unsigned short* W2f  = (unsigned short*)(ws + 1024 + 131072);

  hipLaunchKernelGGL(prep_c1, dim3(1), dim3(256), 0, stream, w1e, b1e, w2e, b2e, w1f, b1f, c1);
  hipLaunchKernelGGL(prep_w, dim3(32), dim3(256), 0, stream, w1f, w2f, W1f, W2f);
  hipLaunchKernelGGL(heal_main, dim3(NBLK), dim3(512), 0, stream,
                     x, edge_src, c1, W1f, W2f, b2f, out);
}

// Round 3
// 397.506 us; speedup vs baseline: 1.0434x; 1.0434x over previous
//
#include <hip/hip_runtime.h>

#define NSND  49152
#define NRECV 115200
#define BM    64
#define BLKS_PER_BATCH 1800  // 115200 / 64
#define NBLK  3600           // 2 * 1800

typedef __bf16 bx8 __attribute__((ext_vector_type(8)));
typedef float  fx4 __attribute__((ext_vector_type(4)));

__device__ __forceinline__ unsigned short f2bf(float f) {
  unsigned u = __float_as_uint(f);
  u += 0x7FFFu + ((u >> 16) & 1u);   // round-to-nearest-even
  return (unsigned short)(u >> 16);
}

// ---------- prep 1: c1[n] = b1f[n] + sum_i ef_sum[i] * w1f[256+i][n] ----------
__global__ void prep_c1(const float* __restrict__ w1e, const float* __restrict__ b1e,
                        const float* __restrict__ w2e, const float* __restrict__ b2e,
                        const float* __restrict__ w1f, const float* __restrict__ b1f,
                        float* __restrict__ c1) {
  __shared__ float s_sum[64];
  __shared__ float s_ef[64];
  int t = threadIdx.x;
  if (t < 64) {
    float w = w1e[t], b = b1e[t];
    float acc = 0.f;
    for (int k = 0; k < 4; ++k) {
      float v = (float)k * w + b;
      acc += v / (1.f + expf(-v));      // silu, summed over the 4 edge-attr values
    }
    s_sum[t] = acc;
  }
  __syncthreads();
  if (t < 64) {
    float acc = 4.f * b2e[t];
    for (int j = 0; j < 64; ++j) acc += s_sum[j] * w2e[j * 64 + t];
    s_ef[t] = acc;
  }
  __syncthreads();
  if (t < 256) {
    float acc = b1f[t];
    for (int i = 0; i < 64; ++i) acc += s_ef[i] * w1f[(256 + i) * 256 + t];
    c1[t] = acc;
  }
}

// ---------- prep 2: weights -> bf16, MFMA-B-fragment-contiguous layout ----------
// Layout: frag[ct (16 col-tiles)][ks (8 k-steps)][lane (64)][8 bf16]
//   element = W[k][n], n = ct*16 + (lane&15), k = ks*32 + (lane>>4)*8 + j
__global__ void prep_w(const float* __restrict__ w1f, const float* __restrict__ w2f,
                       unsigned short* __restrict__ W1f, unsigned short* __restrict__ W2f) {
  int idx  = blockIdx.x * blockDim.x + threadIdx.x;   // 0..8191
  int lane = idx & 63;
  int ks   = (idx >> 6) & 7;
  int ct   = idx >> 9;
  int n     = ct * 16 + (lane & 15);
  int kbase = ks * 32 + (lane >> 4) * 8;
  unsigned p1[4], p2[4];
#pragma unroll
  for (int h = 0; h < 4; ++h) {
    int k = kbase + 2 * h;
    p1[h] = (unsigned)f2bf(w1f[k * 256 + n]) | ((unsigned)f2bf(w1f[(k + 1) * 256 + n]) << 16);
    p2[h] = (unsigned)f2bf(w2f[k * 256 + n]) | ((unsigned)f2bf(w2f[(k + 1) * 256 + n]) << 16);
  }
  uint4 v1 = make_uint4(p1[0], p1[1], p1[2], p1[3]);
  uint4 v2 = make_uint4(p2[0], p2[1], p2[2], p2[3]);
  *(uint4*)(W1f + (size_t)idx * 8) = v1;
  *(uint4*)(W2f + (size_t)idx * 8) = v2;
}

// ---------- main fused kernel: ZERO barriers ----------
// grid 3600, block 256 (4 waves). Each wave owns 16 receiver rows end-to-end:
// gather -> GEMM1 (full 256-wide) -> silu -> GEMM2 -> store. Waves touch only
// their private 8 KiB LDS slice (rows wv*16..+16), so no __syncthreads at all;
// per-wave in-order DS pipe makes intra-wave RAW through LDS safe.
// LDS tile 64x256 bf16, XOR-swizzled: byte(row,col) = (row*512 + col*2) ^ ((row&7)<<4)
// NOTE: the XOR touches bits 4-6 of the address, so it MUST be applied to the
// fully-formed linear offset (including ks*64) — adding after XOR corrupts bit 6.
__global__ __launch_bounds__(256, 4) void heal_main(
    const float* __restrict__ x, const int* __restrict__ edge_src,
    const float* __restrict__ c1, const unsigned short* __restrict__ W1f,
    const unsigned short* __restrict__ W2f, const float* __restrict__ b2f,
    float* __restrict__ out) {
  __shared__ char lds[BM * 512];   // 32 KiB

  const int tid  = threadIdx.x;
  const int lane = tid & 63;
  const int wv   = tid >> 6;       // 0..3

  const int blk = blockIdx.x;
  const int b   = blk / BLKS_PER_BATCH;
  const int r0  = (blk % BLKS_PER_BATCH) * BM;
  const float* xb = x + (size_t)b * NSND * 256;

  // ---- phase 1: gather-sum 4 source rows per receiver -> bf16 A slice in LDS ----
#pragma unroll 4
  for (int i = 0; i < 16; ++i) {
    int row = wv * 16 + i;
    int r   = r0 + row;
    int4 s  = *(const int4*)(edge_src + 4 * (size_t)r);
    const float4* q0 = (const float4*)(xb + (size_t)s.x * 256) + lane;
    const float4* q1 = (const float4*)(xb + (size_t)s.y * 256) + lane;
    const float4* q2 = (const float4*)(xb + (size_t)s.z * 256) + lane;
    const float4* q3 = (const float4*)(xb + (size_t)s.w * 256) + lane;
    float4 a0 = *q0, a1 = *q1, a2 = *q2, a3 = *q3;
    float v0 = a0.x + a1.x + a2.x + a3.x;
    float v1 = a0.y + a1.y + a2.y + a3.y;
    float v2 = a0.z + a1.z + a2.z + a3.z;
    float v3 = a0.w + a1.w + a2.w + a3.w;
    unsigned lo = (unsigned)f2bf(v0) | ((unsigned)f2bf(v1) << 16);
    unsigned hi = (unsigned)f2bf(v2) | ((unsigned)f2bf(v3) << 16);
    unsigned byte = (unsigned)(row * 512 + lane * 8) ^ (unsigned)((row & 7) << 4);
    *(uint2*)(lds + byte) = make_uint2(lo, hi);
  }
  // no barrier: this wave reads only the rows it just wrote (in-order DS pipe)

  fx4 acc[16];
#pragma unroll
  for (int nc = 0; nc < 16; ++nc) acc[nc] = (fx4){0.f, 0.f, 0.f, 0.f};

  // ---- phase 2: GEMM1  (A[16x256] @ W1[256x256], full width per wave) ----
  const bx8* W1v = (const bx8*)W1f;
  const int arow = wv * 16 + (lane & 15);
  const unsigned aswz = (unsigned)((arow & 7) << 4);
  const unsigned alin = (unsigned)(arow * 512 + (lane >> 4) * 16);
#pragma unroll
  for (int ks = 0; ks < 8; ++ks) {
    bx8 afr = *(const bx8*)(lds + ((alin + ks * 64) ^ aswz));
#pragma unroll
    for (int nc = 0; nc < 16; ++nc) {
      bx8 bfr = W1v[(nc * 8 + ks) * 64 + lane];
      acc[nc] = __builtin_amdgcn_mfma_f32_16x16x32_bf16(afr, bfr, acc[nc], 0, 0, 0);
    }
  }

  // ---- phase 3: h = silu(acc + c1) -> bf16 H back into same LDS slice ----
  float c1v[16];
#pragma unroll
  for (int nc = 0; nc < 16; ++nc) c1v[nc] = c1[nc * 16 + (lane & 15)];
#pragma unroll
  for (int nc = 0; nc < 16; ++nc) {
    int hcol = nc * 16 + (lane & 15);
#pragma unroll
    for (int j = 0; j < 4; ++j) {
      float v = acc[nc][j] + c1v[nc];
      float h = v / (1.f + __expf(-v));            // silu
      int hrow = wv * 16 + (lane >> 4) * 4 + j;
      unsigned hb = (unsigned)(hrow * 512 + hcol * 2) ^ (unsigned)((hrow & 7) << 4);
      *(unsigned short*)(lds + hb) = f2bf(h);
    }
  }

  // ---- phase 4: GEMM2  (H[16x256] @ W2[256x256]) ----
#pragma unroll
  for (int nc = 0; nc < 16; ++nc) acc[nc] = (fx4){0.f, 0.f, 0.f, 0.f};
  const bx8* W2v = (const bx8*)W2f;
#pragma unroll
  for (int ks = 0; ks < 8; ++ks) {
    bx8 afr = *(const bx8*)(lds + ((alin + ks * 64) ^ aswz));
#pragma unroll
    for (int nc = 0; nc < 16; ++nc) {
      bx8 bfr = W2v[(nc * 8 + ks) * 64 + lane];
      acc[nc] = __builtin_amdgcn_mfma_f32_16x16x32_bf16(afr, bfr, acc[nc], 0, 0, 0);
    }
  }

  // ---- phase 5: out = acc + b2f ----
  size_t obase = ((size_t)b * NRECV + r0) * 256;
#pragma unroll
  for (int nc = 0; nc < 16; ++nc) {
    int col = nc * 16 + (lane & 15);
    float bias = b2f[col];
#pragma unroll
    for (int j = 0; j < 4; ++j) {
      int row = wv * 16 + (lane >> 4) * 4 + j;
      out[obase + (size_t)row * 256 + col] = acc[nc][j] + bias;
    }
  }
}

extern "C" void kernel_launch(void* const* d_in, const int* in_sizes, int n_in,
                              void* d_out, int out_size, void* d_ws, size_t ws_size,
                              hipStream_t stream) {
  const float* x    = (const float*)d_in[0];
  const float* w1e  = (const float*)d_in[2];
  const float* b1e  = (const float*)d_in[3];
  const float* w2e  = (const float*)d_in[4];
  const float* b2e  = (const float*)d_in[5];
  const float* w1f  = (const float*)d_in[6];
  const float* b1f  = (const float*)d_in[7];
  const float* w2f  = (const float*)d_in[8];
  const float* b2f  = (const float*)d_in[9];
  const int* edge_src = (const int*)d_in[10];
  float* out = (float*)d_out;

  char* ws = (char*)d_ws;
  float* c1            = (float*)ws;                          // 1 KiB
  unsigned short* W1f  = (unsigned short*)(ws + 1024);        // 128 KiB
  unsigned short* W2f  = (unsigned short*)(ws + 1024 + 131072);

  hipLaunchKernelGGL(prep_c1, dim3(1), dim3(256), 0, stream, w1e, b1e, w2e, b2e, w1f, b1f, c1);
  hipLaunchKernelGGL(prep_w, dim3(32), dim3(256), 0, stream, w1f, w2f, W1f, W2f);
  hipLaunchKernelGGL(heal_main, dim3(NBLK), dim3(256), 0, stream,
                     x, edge_src, c1, W1f, W2f, b2f, out);
}

// Round 5
// 291.143 us; speedup vs baseline: 1.4246x; 1.3653x over previous
//
#include <hip/hip_runtime.h>

#define NSND   49152
#define NRECV  115200
#define NSROWS (2 * NSND)     // 98304 dense sender rows (both batches)
#define NRROWS (2 * NRECV)    // 230400 receiver rows

typedef __bf16 bx8 __attribute__((ext_vector_type(8)));
typedef float  fx4 __attribute__((ext_vector_type(4)));

__device__ __forceinline__ unsigned short f2bf(float f) {
  unsigned u = __float_as_uint(f);
  u += 0x7FFFu + ((u >> 16) & 1u);   // round-to-nearest-even
  return (unsigned short)(u >> 16);
}

// ---------- prep 1: c1[n] = b1f[n] + sum_i ef_sum[i] * w1f[256+i][n] ----------
__global__ void prep_c1(const float* __restrict__ w1e, const float* __restrict__ b1e,
                        const float* __restrict__ w2e, const float* __restrict__ b2e,
                        const float* __restrict__ w1f, const float* __restrict__ b1f,
                        float* __restrict__ c1) {
  __shared__ float s_sum[64];
  __shared__ float s_ef[64];
  int t = threadIdx.x;
  if (t < 64) {
    float w = w1e[t], b = b1e[t];
    float acc = 0.f;
    for (int k = 0; k < 4; ++k) {
      float v = (float)k * w + b;
      acc += v / (1.f + expf(-v));      // silu over the 4 edge-attr values
    }
    s_sum[t] = acc;
  }
  __syncthreads();
  if (t < 64) {
    float acc = 4.f * b2e[t];
    for (int j = 0; j < 64; ++j) acc += s_sum[j] * w2e[j * 64 + t];
    s_ef[t] = acc;
  }
  __syncthreads();
  if (t < 256) {
    float acc = b1f[t];
    for (int i = 0; i < 64; ++i) acc += s_ef[i] * w1f[(256 + i) * 256 + t];
    c1[t] = acc;
  }
}

// ---------- prep 2: weights -> bf16, MFMA-B-fragment-contiguous layout ----------
// frag[ct(16)][ks(8)][lane(64)][8 bf16]; element = W[k][n], n=ct*16+(lane&15),
// k = ks*32 + (lane>>4)*8 + j
__global__ void prep_w(const float* __restrict__ w1f, const float* __restrict__ w2f,
                       unsigned short* __restrict__ W1f, unsigned short* __restrict__ W2f) {
  int idx  = blockIdx.x * blockDim.x + threadIdx.x;   // 0..8191
  int lane = idx & 63;
  int ks   = (idx >> 6) & 7;
  int ct   = idx >> 9;
  int n     = ct * 16 + (lane & 15);
  int kbase = ks * 32 + (lane >> 4) * 8;
  unsigned p1[4], p2[4];
#pragma unroll
  for (int h = 0; h < 4; ++h) {
    int k = kbase + 2 * h;
    p1[h] = (unsigned)f2bf(w1f[k * 256 + n]) | ((unsigned)f2bf(w1f[(k + 1) * 256 + n]) << 16);
    p2[h] = (unsigned)f2bf(w2f[k * 256 + n]) | ((unsigned)f2bf(w2f[(k + 1) * 256 + n]) << 16);
  }
  *(uint4*)(W1f + (size_t)idx * 8) = make_uint4(p1[0], p1[1], p1[2], p1[3]);
  *(uint4*)(W2f + (size_t)idx * 8) = make_uint4(p2[0], p2[1], p2[2], p2[3]);
}

// ---------- K1: Y' = x @ W1 + c1/4  (dense, 98304 sender rows, bf16 out) ----------
// grid 1536, block 256 (4 waves), 16 rows/wave, zero barriers (wave-private slices)
__global__ __launch_bounds__(256, 4) void k1_senders(
    const float* __restrict__ x, const float* __restrict__ c1,
    const unsigned short* __restrict__ W1f, unsigned short* __restrict__ Yp) {
  __shared__ char lds[64 * 512];   // 32 KiB

  const int lane = threadIdx.x & 63;
  const int wv   = threadIdx.x >> 6;
  const int rb   = blockIdx.x * 64;           // global row base of block

  // stage 16 x-rows -> bf16 LDS (swizzled)
#pragma unroll 4
  for (int i = 0; i < 16; ++i) {
    int row = wv * 16 + i;
    const fx4* q = (const fx4*)(x + (size_t)(rb + row) * 256) + lane;
    fx4 a = __builtin_nontemporal_load(q);
    unsigned lo = (unsigned)f2bf(a.x) | ((unsigned)f2bf(a.y) << 16);
    unsigned hi = (unsigned)f2bf(a.z) | ((unsigned)f2bf(a.w) << 16);
    unsigned byte = (unsigned)(row * 512 + lane * 8) ^ (unsigned)((row & 7) << 4);
    *(uint2*)(lds + byte) = make_uint2(lo, hi);
  }

  fx4 acc[16];
#pragma unroll
  for (int nc = 0; nc < 16; ++nc) acc[nc] = (fx4){0.f, 0.f, 0.f, 0.f};

  const bx8* W1v = (const bx8*)W1f;
  const int arow = wv * 16 + (lane & 15);
  const unsigned aswz = (unsigned)((arow & 7) << 4);
  const unsigned alin = (unsigned)(arow * 512 + (lane >> 4) * 16);
#pragma unroll
  for (int ks = 0; ks < 8; ++ks) {
    bx8 afr = *(const bx8*)(lds + ((alin + ks * 64) ^ aswz));
#pragma unroll
    for (int nc = 0; nc < 16; ++nc) {
      bx8 bfr = W1v[(nc * 8 + ks) * 64 + lane];
      acc[nc] = __builtin_amdgcn_mfma_f32_16x16x32_bf16(afr, bfr, acc[nc], 0, 0, 0);
    }
  }

  // Y'(row) = acc + c1/4 -> bf16 into LDS (swizzled), then coalesced store
#pragma unroll
  for (int nc = 0; nc < 16; ++nc) {
    float c1q = 0.25f * c1[nc * 16 + (lane & 15)];
    int col = nc * 16 + (lane & 15);
#pragma unroll
    for (int j = 0; j < 4; ++j) {
      int row = wv * 16 + (lane >> 4) * 4 + j;
      unsigned hb = (unsigned)(row * 512 + col * 2) ^ (unsigned)((row & 7) << 4);
      *(unsigned short*)(lds + hb) = f2bf(acc[nc][j] + c1q);
    }
  }
  // write back 16 rows (8 KiB) coalesced: 8 × 16B per lane
#pragma unroll
  for (int t = 0; t < 8; ++t) {
    int task  = t * 64 + lane;
    int row   = wv * 16 + (task >> 5);
    int chunk = task & 31;
    unsigned byte = (unsigned)(row * 512 + chunk * 16) ^ (unsigned)((row & 7) << 4);
    uint4 v = *(const uint4*)(lds + byte);
    *(uint4*)(Yp + ((size_t)(rb + row)) * 256 + chunk * 8) = v;
  }
}

// ---------- K23: gather-sum Y' -> silu -> GEMM2 -> out (nt stores) ----------
// grid 3600, block 256 (4 waves), 16 receiver rows/wave, zero barriers
__global__ __launch_bounds__(256, 4) void k23_recv(
    const unsigned short* __restrict__ Yp, const int* __restrict__ edge_src,
    const unsigned short* __restrict__ W2f, const float* __restrict__ b2f,
    float* __restrict__ out) {
  __shared__ char lds[64 * 512];   // 32 KiB

  const int lane = threadIdx.x & 63;
  const int wv   = threadIdx.x >> 6;

  const int blk = blockIdx.x;
  const int b   = blk / 1800;                  // batch
  const int rr0 = (blk % 1800) * 64;           // receiver row base within batch
  const size_t ybase = (size_t)b * NSND * 256; // Y' batch offset (elements)
  const int4* esrc4 = (const int4*)edge_src;

  // gather phase: 8 tasks/lane, task = (row_i in [0,16), chunk in [0,32))
#pragma unroll 2
  for (int t = 0; t < 8; ++t) {
    int task  = t * 64 + lane;
    int row_i = task >> 5;                     // 0..15
    int chunk = task & 31;                     // 16B chunk within 512B row
    int4 s = esrc4[rr0 + wv * 16 + row_i];
    bx8 a0 = *(const bx8*)(Yp + ybase + (size_t)s.x * 256 + chunk * 8);
    bx8 a1 = *(const bx8*)(Yp + ybase + (size_t)s.y * 256 + chunk * 8);
    bx8 a2 = *(const bx8*)(Yp + ybase + (size_t)s.z * 256 + chunk * 8);
    bx8 a3 = *(const bx8*)(Yp + ybase + (size_t)s.w * 256 + chunk * 8);
    unsigned p[4];
#pragma unroll
    for (int h = 0; h < 4; ++h) {
      float v0 = (float)a0[2*h] + (float)a1[2*h] + (float)a2[2*h] + (float)a3[2*h];
      float v1 = (float)a0[2*h+1] + (float)a1[2*h+1] + (float)a2[2*h+1] + (float)a3[2*h+1];
      float h0 = v0 / (1.f + __expf(-v0));     // silu
      float h1 = v1 / (1.f + __expf(-v1));
      p[h] = (unsigned)f2bf(h0) | ((unsigned)f2bf(h1) << 16);
    }
    int row = wv * 16 + row_i;
    unsigned byte = (unsigned)(row * 512 + chunk * 16) ^ (unsigned)((row & 7) << 4);
    *(uint4*)(lds + byte) = make_uint4(p[0], p[1], p[2], p[3]);
  }

  fx4 acc[16];
#pragma unroll
  for (int nc = 0; nc < 16; ++nc) acc[nc] = (fx4){0.f, 0.f, 0.f, 0.f};

  // GEMM2: H[16x256] @ W2[256x256]
  const bx8* W2v = (const bx8*)W2f;
  const int arow = wv * 16 + (lane & 15);
  const unsigned aswz = (unsigned)((arow & 7) << 4);
  const unsigned alin = (unsigned)(arow * 512 + (lane >> 4) * 16);
#pragma unroll
  for (int ks = 0; ks < 8; ++ks) {
    bx8 afr = *(const bx8*)(lds + ((alin + ks * 64) ^ aswz));
#pragma unroll
    for (int nc = 0; nc < 16; ++nc) {
      bx8 bfr = W2v[(nc * 8 + ks) * 64 + lane];
      acc[nc] = __builtin_amdgcn_mfma_f32_16x16x32_bf16(afr, bfr, acc[nc], 0, 0, 0);
    }
  }

  // epilogue: out = acc + b2f, non-temporal (don't pollute L3 -> keep Y' hot)
  size_t obase = ((size_t)b * NRECV + rr0) * 256;
#pragma unroll
  for (int nc = 0; nc < 16; ++nc) {
    int col = nc * 16 + (lane & 15);
    float bias = b2f[col];
#pragma unroll
    for (int j = 0; j < 4; ++j) {
      int row = wv * 16 + (lane >> 4) * 4 + j;
      __builtin_nontemporal_store(acc[nc][j] + bias, &out[obase + (size_t)row * 256 + col]);
    }
  }
}

// ---------- fallback (R3-validated fused kernel) if ws is too small ----------
__global__ __launch_bounds__(256, 4) void heal_fused(
    const float* __restrict__ x, const int* __restrict__ edge_src,
    const float* __restrict__ c1, const unsigned short* __restrict__ W1f,
    const unsigned short* __restrict__ W2f, const float* __restrict__ b2f,
    float* __restrict__ out) {
  __shared__ char lds[64 * 512];
  const int lane = threadIdx.x & 63;
  const int wv   = threadIdx.x >> 6;
  const int blk = blockIdx.x;
  const int b   = blk / 1800;
  const int r0  = (blk % 1800) * 64;
  const float* xb = x + (size_t)b * NSND * 256;
#pragma unroll 4
  for (int i = 0; i < 16; ++i) {
    int row = wv * 16 + i;
    int r   = r0 + row;
    int4 s  = *(const int4*)(edge_src + 4 * (size_t)r);
    float4 a0 = *((const float4*)(xb + (size_t)s.x * 256) + lane);
    float4 a1 = *((const float4*)(xb + (size_t)s.y * 256) + lane);
    float4 a2 = *((const float4*)(xb + (size_t)s.z * 256) + lane);
    float4 a3 = *((const float4*)(xb + (size_t)s.w * 256) + lane);
    float v0 = a0.x + a1.x + a2.x + a3.x;
    float v1 = a0.y + a1.y + a2.y + a3.y;
    float v2 = a0.z + a1.z + a2.z + a3.z;
    float v3 = a0.w + a1.w + a2.w + a3.w;
    unsigned lo = (unsigned)f2bf(v0) | ((unsigned)f2bf(v1) << 16);
    unsigned hi = (unsigned)f2bf(v2) | ((unsigned)f2bf(v3) << 16);
    unsigned byte = (unsigned)(row * 512 + lane * 8) ^ (unsigned)((row & 7) << 4);
    *(uint2*)(lds + byte) = make_uint2(lo, hi);
  }
  fx4 acc[16];
#pragma unroll
  for (int nc = 0; nc < 16; ++nc) acc[nc] = (fx4){0.f, 0.f, 0.f, 0.f};
  const bx8* W1v = (const bx8*)W1f;
  const int arow = wv * 16 + (lane & 15);
  const unsigned aswz = (unsigned)((arow & 7) << 4);
  const unsigned alin = (unsigned)(arow * 512 + (lane >> 4) * 16);
#pragma unroll
  for (int ks = 0; ks < 8; ++ks) {
    bx8 afr = *(const bx8*)(lds + ((alin + ks * 64) ^ aswz));
#pragma unroll
    for (int nc = 0; nc < 16; ++nc) {
      bx8 bfr = W1v[(nc * 8 + ks) * 64 + lane];
      acc[nc] = __builtin_amdgcn_mfma_f32_16x16x32_bf16(afr, bfr, acc[nc], 0, 0, 0);
    }
  }
  float c1v[16];
#pragma unroll
  for (int nc = 0; nc < 16; ++nc) c1v[nc] = c1[nc * 16 + (lane & 15)];
#pragma unroll
  for (int nc = 0; nc < 16; ++nc) {
    int hcol = nc * 16 + (lane & 15);
#pragma unroll
    for (int j = 0; j < 4; ++j) {
      float v = acc[nc][j] + c1v[nc];
      float h = v / (1.f + __expf(-v));
      int hrow = wv * 16 + (lane >> 4) * 4 + j;
      unsigned hb = (unsigned)(hrow * 512 + hcol * 2) ^ (unsigned)((hrow & 7) << 4);
      *(unsigned short*)(lds + hb) = f2bf(h);
    }
  }
#pragma unroll
  for (int nc = 0; nc < 16; ++nc) acc[nc] = (fx4){0.f, 0.f, 0.f, 0.f};
  const bx8* W2v = (const bx8*)W2f;
#pragma unroll
  for (int ks = 0; ks < 8; ++ks) {
    bx8 afr = *(const bx8*)(lds + ((alin + ks * 64) ^ aswz));
#pragma unroll
    for (int nc = 0; nc < 16; ++nc) {
      bx8 bfr = W2v[(nc * 8 + ks) * 64 + lane];
      acc[nc] = __builtin_amdgcn_mfma_f32_16x16x32_bf16(afr, bfr, acc[nc], 0, 0, 0);
    }
  }
  size_t obase = ((size_t)b * NRECV + r0) * 256;
#pragma unroll
  for (int nc = 0; nc < 16; ++nc) {
    int col = nc * 16 + (lane & 15);
    float bias = b2f[col];
#pragma unroll
    for (int j = 0; j < 4; ++j) {
      int row = wv * 16 + (lane >> 4) * 4 + j;
      out[obase + (size_t)row * 256 + col] = acc[nc][j] + bias;
    }
  }
}

extern "C" void kernel_launch(void* const* d_in, const int* in_sizes, int n_in,
                              void* d_out, int out_size, void* d_ws, size_t ws_size,
                              hipStream_t stream) {
  const float* x    = (const float*)d_in[0];
  const float* w1e  = (const float*)d_in[2];
  const float* b1e  = (const float*)d_in[3];
  const float* w2e  = (const float*)d_in[4];
  const float* b2e  = (const float*)d_in[5];
  const float* w1f  = (const float*)d_in[6];
  const float* b1f  = (const float*)d_in[7];
  const float* w2f  = (const float*)d_in[8];
  const float* b2f  = (const float*)d_in[9];
  const int* edge_src = (const int*)d_in[10];
  float* out = (float*)d_out;

  char* ws = (char*)d_ws;
  float* c1            = (float*)ws;                       // @0, 1 KiB
  unsigned short* W1f  = (unsigned short*)(ws + 4096);     // 128 KiB
  unsigned short* W2f  = (unsigned short*)(ws + 4096 + 131072);
  unsigned short* Yp   = (unsigned short*)(ws + 1048576);  // 48 MiB bf16 Y'
  const size_t need = 1048576 + (size_t)NSROWS * 256 * 2;

  hipLaunchKernelGGL(prep_c1, dim3(1), dim3(256), 0, stream, w1e, b1e, w2e, b2e, w1f, b1f, c1);
  hipLaunchKernelGGL(prep_w, dim3(32), dim3(256), 0, stream, w1f, w2f, W1f, W2f);
  if (ws_size >= need) {
    hipLaunchKernelGGL(k1_senders, dim3(NSROWS / 64), dim3(256), 0, stream, x, c1, W1f, Yp);
    hipLaunchKernelGGL(k23_recv, dim3(NRROWS / 64), dim3(256), 0, stream,
                       Yp, edge_src, W2f, b2f, out);
  } else {
    hipLaunchKernelGGL(heal_fused, dim3(NRROWS / 64), dim3(256), 0, stream,
                       x, edge_src, c1, W1f, W2f, b2f, out);
  }
}